// Round 1
// baseline (386.816 us; speedup 1.0000x reference)
//
#include <hip/hip_runtime.h>
#include <math.h>

#define CC 10   // classes
#define KK 50   // neighbors

// ---------------- K1: softmax(anchors_weak) -> wap, mask0, b_count ----------
__global__ __launch_bounds__(256)
void k1_wap(const float* __restrict__ aw, float* __restrict__ wap,
            int* __restrict__ flag0, int* __restrict__ b_count, int B)
{
  int i = blockIdx.x * 256 + threadIdx.x;
  if (i >= B) return;
  float x[CC];
  const float2* p = reinterpret_cast<const float2*>(aw + (size_t)i * CC);
#pragma unroll
  for (int c = 0; c < CC / 2; ++c) { float2 t = p[c]; x[2 * c] = t.x; x[2 * c + 1] = t.y; }
  float m = x[0];
#pragma unroll
  for (int c = 1; c < CC; ++c) m = fmaxf(m, x[c]);
  float s = 0.f;
#pragma unroll
  for (int c = 0; c < CC; ++c) { x[c] = expf(x[c] - m); s += x[c]; }
  float mp = 0.f;
#pragma unroll
  for (int c = 0; c < CC; ++c) { x[c] = x[c] / s; mp = fmaxf(mp, x[c]); }
  float2* q = reinterpret_cast<float2*>(wap + (size_t)i * CC);
#pragma unroll
  for (int c = 0; c < CC / 2; ++c) { float2 t; t.x = x[2 * c]; t.y = x[2 * c + 1]; q[c] = t; }
  int f = (mp > 0.15f) ? 1 : 0;
  flag0[i] = f;
  if (f) atomicAdd(b_count, 1);
}

// ---------------- K2: attention over neighbors -> beta[i] -------------------
// one wave (64 lanes) per row; lanes 0..49 handle the K neighbors
__global__ __launch_bounds__(256)
void k2_beta(const float* __restrict__ anchors, const float* __restrict__ neighbors,
             const float* __restrict__ att, const float* __restrict__ proj,
             float* __restrict__ beta, int B)
{
  __shared__ float coef[CC];
  if (threadIdx.x < CC) {
    float d = proj[threadIdx.x * CC + threadIdx.x];
    coef[threadIdx.x] = att[threadIdx.x] * d * d;
  }
  __syncthreads();
  int wave = threadIdx.x >> 6;
  int lane = threadIdx.x & 63;
  int row = blockIdx.x * 4 + wave;
  if (row >= B) return;

  float iv = (lane < CC) ? anchors[(size_t)row * CC + lane] : 0.f;
  float img[CC];
#pragma unroll
  for (int c = 0; c < CC; ++c) img[c] = __shfl(iv, c);

  bool act = (lane < KK);
  float nb[CC];
  if (act) {
    const float2* np_ = reinterpret_cast<const float2*>(neighbors + ((size_t)row * KK + lane) * CC);
#pragma unroll
    for (int c = 0; c < CC / 2; ++c) { float2 t = np_[c]; nb[2 * c] = t.x; nb[2 * c + 1] = t.y; }
  } else {
#pragma unroll
    for (int c = 0; c < CC; ++c) nb[c] = 0.f;
  }

  // att_score = leaky_relu( sum_c att[c]*d[c]^2 * img[c] * nb[c] )
  float s = 0.f;
#pragma unroll
  for (int c = 0; c < CC; ++c) s += coef[c] * img[c] * nb[c];
  s = (s > 0.f) ? s : 0.01f * s;

  // softmax over K (across lanes)
  float sm = act ? s : -INFINITY;
#pragma unroll
  for (int off = 32; off; off >>= 1) sm = fmaxf(sm, __shfl_xor(sm, off));
  float e = act ? expf(s - sm) : 0.f;
  float den = e;
#pragma unroll
  for (int off = 32; off; off >>= 1) den += __shfl_xor(den, off);
  float av = e / den;

  // nbp = softmax over C for this lane's neighbor
  float mx = nb[0];
#pragma unroll
  for (int c = 1; c < CC; ++c) mx = fmaxf(mx, nb[c]);
  float pn[CC]; float sn = 0.f;
#pragma unroll
  for (int c = 0; c < CC; ++c) { pn[c] = expf(nb[c] - mx); sn += pn[c]; }
  float scale = av / sn;
  float v[CC];
#pragma unroll
  for (int c = 0; c < CC; ++c) v[c] = act ? pn[c] * scale : 0.f;

  // q_hat[c] = sum_k att_val[k]*nbp[k,c]  (butterfly per component)
#pragma unroll
  for (int c = 0; c < CC; ++c) {
#pragma unroll
    for (int off = 32; off; off >>= 1) v[c] += __shfl_xor(v[c], off);
  }

  if (lane == 0) {
    float m2 = img[0];
#pragma unroll
    for (int c = 1; c < CC; ++c) m2 = fmaxf(m2, img[c]);
    float s2 = 0.f; float ap[CC];
#pragma unroll
    for (int c = 0; c < CC; ++c) { ap[c] = expf(img[c] - m2); s2 += ap[c]; }
    float bs = 0.f;
#pragma unroll
    for (int c = 0; c < CC; ++c) { float d = ap[c] / s2 - v[c]; bs += d * d; }
    beta[row] = bs;
  }
}

// ---------------- K3: exact radix select of k-th smallest beta --------------
__global__ __launch_bounds__(256)
void k3a_hist(const float* __restrict__ beta, const int* __restrict__ flag0,
              int* __restrict__ hist, int B)
{
  int i = blockIdx.x * 256 + threadIdx.x;
  if (i >= B) return;
  if (flag0[i]) {
    unsigned key = __float_as_uint(beta[i]);   // beta >= 0 -> bits are order-preserving
    atomicAdd(&hist[key >> 16], 1);
  }
}

// scal: [0]=b_count [1]=n_count [2]=sel_hi [3]=k2 [4]=k ; (float at [8]) = tau
__global__ __launch_bounds__(1024)
void k3b_sel(const int* __restrict__ hist, int* __restrict__ scal)
{
  __shared__ int tmp[1024];
  int t = threadIdx.x;
  int base = t * 64;
  int sum = 0;
  for (int j = 0; j < 64; ++j) sum += hist[base + j];
  tmp[t] = sum;
  __syncthreads();
  for (int off = 1; off < 1024; off <<= 1) {
    int v = (t >= off) ? tmp[t - off] : 0;
    __syncthreads();
    tmp[t] += v;
    __syncthreads();
  }
  int cumb = tmp[t] - sum;
  int b = scal[0];
  int k = (int)(0.5 * (double)b);   // int(ETA*b)
  if (k < 1) k = 1;
  if (t == 0) scal[4] = k;
  if (b > 0 && k > cumb && k <= cumb + sum) {
    int c = cumb;
    for (int j = 0; j < 64; ++j) {
      int h = hist[base + j];
      if (k <= c + h) { scal[2] = base + j; scal[3] = k - c; break; }
      c += h;
    }
  }
  if (b == 0 && t == 0) { scal[2] = 0; scal[3] = 1; }
}

__global__ __launch_bounds__(256)
void k3c_hist2(const float* __restrict__ beta, const int* __restrict__ flag0,
               const int* __restrict__ scal, int* __restrict__ hist2, int B)
{
  int i = blockIdx.x * 256 + threadIdx.x;
  if (i >= B) return;
  if (flag0[i]) {
    unsigned key = __float_as_uint(beta[i]);
    if ((int)(key >> 16) == scal[2]) atomicAdd(&hist2[key & 0xFFFF], 1);
  }
}

__global__ __launch_bounds__(1024)
void k3d_tau(const int* __restrict__ hist2, int* __restrict__ scal,
             float* __restrict__ tau)
{
  __shared__ int tmp[1024];
  int t = threadIdx.x;
  int base = t * 64;
  int sum = 0;
  for (int j = 0; j < 64; ++j) sum += hist2[base + j];
  tmp[t] = sum;
  __syncthreads();
  for (int off = 1; off < 1024; off <<= 1) {
    int v = (t >= off) ? tmp[t - off] : 0;
    __syncthreads();
    tmp[t] += v;
    __syncthreads();
  }
  int cumb = tmp[t] - sum;
  int k2 = scal[3];
  if (k2 > cumb && k2 <= cumb + sum) {
    int c = cumb;
    for (int j = 0; j < 64; ++j) {
      int h = hist2[base + j];
      if (k2 <= c + h) {
        unsigned key = (((unsigned)scal[2]) << 16) | (unsigned)(base + j);
        float bk = __uint_as_float(key);
        *tau = bk / expf(-1.0f);
        break;
      }
      c += h;
    }
  }
}

// ---------------- K4: q, target, mask1, counts ------------------------------
__global__ __launch_bounds__(256)
void k4_q(const float* __restrict__ wap, const float* __restrict__ beta,
          const int* __restrict__ flag0, const float* __restrict__ tau_p,
          float* __restrict__ qbuf, int* __restrict__ target, int* __restrict__ flag1,
          int* __restrict__ n_count, int* __restrict__ counts,
          int* __restrict__ blockcnt, int B)
{
  int i = blockIdx.x * 256 + threadIdx.x;
  int f = 0;
  if (i < B) {
    float tau = *tau_p;
    float w[CC];
    const float2* p = reinterpret_cast<const float2*>(wap + (size_t)i * CC);
#pragma unroll
    for (int c = 0; c < CC / 2; ++c) { float2 t = p[c]; w[2 * c] = t.x; w[2 * c + 1] = t.y; }
    float alpha = -logf(beta[i] / tau);
    float q[CC];
    if (alpha > 1.0f) {
      float s = 0.f;
#pragma unroll
      for (int c = 0; c < CC; ++c) { q[c] = powf(w[c], alpha); s += q[c]; }
#pragma unroll
      for (int c = 0; c < CC; ++c) q[c] = q[c] / s;
    } else {
#pragma unroll
      for (int c = 0; c < CC; ++c) q[c] = w[c];
    }
    float mp = q[0]; int tg = 0;
#pragma unroll
    for (int c = 1; c < CC; ++c) if (q[c] > mp) { mp = q[c]; tg = c; }
    f = (flag0[i] && (mp > 0.1f)) ? 1 : 0;
    float2* qo = reinterpret_cast<float2*>(qbuf + (size_t)i * CC);
#pragma unroll
    for (int c = 0; c < CC / 2; ++c) { float2 t; t.x = q[2 * c]; t.y = q[2 * c + 1]; qo[c] = t; }
    target[i] = tg;
    flag1[i] = f;
    if (f) { atomicAdd(n_count, 1); atomicAdd(&counts[tg], 1); }
  }
  __shared__ int red[256];
  red[threadIdx.x] = f;
  __syncthreads();
  for (int off = 128; off; off >>= 1) {
    if (threadIdx.x < off) red[threadIdx.x] += red[threadIdx.x + off];
    __syncthreads();
  }
  if (threadIdx.x == 0) blockcnt[blockIdx.x] = red[0];
}

// ---------------- K5: scan block counts; class weights ----------------------
__global__ __launch_bounds__(256)
void k5_scan(const int* __restrict__ blockcnt, int* __restrict__ blockoff, int nb,
             const int* __restrict__ counts, const int* __restrict__ n_count,
             float* __restrict__ wavg)
{
  __shared__ int tmp[256];
  int t = threadIdx.x;
  int v = (t < nb) ? blockcnt[t] : 0;
  tmp[t] = v;
  __syncthreads();
  for (int off = 1; off < 256; off <<= 1) {
    int u = (t >= off) ? tmp[t - off] : 0;
    __syncthreads();
    tmp[t] += u;
    __syncthreads();
  }
  if (t < nb) blockoff[t] = tmp[t] - v;
  if (t == 0) {
    int n = *n_count;
    float wt[CC]; float sumw = 0.f;
    for (int c = 0; c < CC; ++c) {
      int cnt = counts[c];
      float w_;
      if (cnt > 0) {
        float freq = (float)cnt / (float)n;
        w_ = 1.0f / logf(1.02f + freq);
      } else {
        w_ = 1.0f;
      }
      wt[c] = w_; sumw += w_;
    }
    float meanw = sumw / (float)CC;
    for (int c = 0; c < CC; ++c) wavg[c] = wt[c] / sumw * meanw;
  }
}

// ---------------- K6: compacted outputs + loss partials ---------------------
__global__ __launch_bounds__(256)
void k6_out(const int* __restrict__ flag1, const int* __restrict__ target,
            const int* __restrict__ labels, const int* __restrict__ blockoff,
            const float* __restrict__ a_strong, const float* __restrict__ qbuf,
            const float* __restrict__ wavg, float* __restrict__ out,
            float* __restrict__ lossp, int n_host, int B)
{
  int i = blockIdx.x * 256 + threadIdx.x;
  int t = threadIdx.x;
  int f = (i < B) ? flag1[i] : 0;
  __shared__ int tmp[256];
  tmp[t] = f;
  __syncthreads();
  for (int off = 1; off < 256; off <<= 1) {
    int u = (t >= off) ? tmp[t - off] : 0;
    __syncthreads();
    tmp[t] += u;
    __syncthreads();
  }
  int pos = blockoff[blockIdx.x] + tmp[t] - f;
  float part = 0.f;
  if (f) {
    out[1 + pos] = (float)target[i];
    out[1 + n_host + pos] = (float)labels[i];
    float x[CC];
    const float2* p = reinterpret_cast<const float2*>(a_strong + (size_t)i * CC);
#pragma unroll
    for (int c = 0; c < CC / 2; ++c) { float2 u2 = p[c]; x[2 * c] = u2.x; x[2 * c + 1] = u2.y; }
    float m = x[0];
#pragma unroll
    for (int c = 1; c < CC; ++c) m = fmaxf(m, x[c]);
    float s = 0.f;
#pragma unroll
    for (int c = 0; c < CC; ++c) s += expf(x[c] - m);
    float lse = m + logf(s);
    const float2* qp = reinterpret_cast<const float2*>(qbuf + (size_t)i * CC);
    float q[CC];
#pragma unroll
    for (int c = 0; c < CC / 2; ++c) { float2 u2 = qp[c]; q[2 * c] = u2.x; q[2 * c + 1] = u2.y; }
#pragma unroll
    for (int c = 0; c < CC; ++c) part += wavg[c] * q[c] * (x[c] - lse);
  }
  __shared__ float red[256];
  red[t] = part;
  __syncthreads();
  for (int off = 128; off; off >>= 1) {
    if (t < off) red[t] += red[t + off];
    __syncthreads();
  }
  if (t == 0) lossp[blockIdx.x] = red[0];
}

// ---------------- K7: finalize ----------------------------------------------
__global__ __launch_bounds__(256)
void k7_fin(const float* __restrict__ lossp, int nb, const int* __restrict__ n_count,
            float* __restrict__ out, int n_host)
{
  __shared__ float red[256];
  int t = threadIdx.x;
  float s = 0.f;
  for (int j = t; j < nb; j += 256) s += lossp[j];
  red[t] = s;
  __syncthreads();
  for (int off = 128; off; off >>= 1) {
    if (t < off) red[t] += red[t + off];
    __syncthreads();
  }
  if (t == 0) {
    int n = *n_count;
    out[0] = -red[0] / (float)n;
    out[1 + 2 * n_host] = (float)n;
  }
}

extern "C" void kernel_launch(void* const* d_in, const int* in_sizes, int n_in,
                              void* d_out, int out_size, void* d_ws, size_t ws_size,
                              hipStream_t stream)
{
  const float* aw     = (const float*)d_in[0];
  const float* astr   = (const float*)d_in[1];
  const float* an     = (const float*)d_in[2];
  const float* nbr    = (const float*)d_in[3];
  const int*   labels = (const int*)d_in[4];
  const float* att    = (const float*)d_in[6];
  const float* proj   = (const float*)d_in[7];
  float* out = (float*)d_out;

  int B = in_sizes[4];
  int C = in_sizes[6];
  int K = (B > 0 && C > 0) ? in_sizes[3] / (B * C) : 0;
  if (C != CC || K != KK) return;
  int n_host = (out_size - 2) / 2;
  int nb = (B + 255) / 256;
  if (nb > 256) return;

  char* w = (char*)d_ws;
  size_t o = 0;
  auto alloc = [&](size_t bytes) { size_t r = o; o += (bytes + 255) & ~(size_t)255; return r; };
  size_t o_wap  = alloc((size_t)B * CC * 4);
  size_t o_q    = alloc((size_t)B * CC * 4);
  size_t o_beta = alloc((size_t)B * 4);
  size_t o_tgt  = alloc((size_t)B * 4);
  size_t o_f0   = alloc((size_t)B * 4);
  size_t o_f1   = alloc((size_t)B * 4);
  size_t o_bc   = alloc((size_t)nb * 4);
  size_t o_bo   = alloc((size_t)nb * 4);
  size_t o_lp   = alloc((size_t)nb * 4);
  size_t o_wavg = alloc(64);
  size_t zstart = o;
  size_t o_h1   = alloc(65536 * 4);
  size_t o_h2   = alloc(65536 * 4);
  size_t o_cnt  = alloc(64);
  size_t o_scal = alloc(64);
  size_t ztotal = o - zstart;
  if (o > ws_size) return;

  float* wap   = (float*)(w + o_wap);
  float* qbuf  = (float*)(w + o_q);
  float* beta  = (float*)(w + o_beta);
  int*   tgt   = (int*)(w + o_tgt);
  int*   f0    = (int*)(w + o_f0);
  int*   f1    = (int*)(w + o_f1);
  int*   bcnt  = (int*)(w + o_bc);
  int*   boff  = (int*)(w + o_bo);
  float* lossp = (float*)(w + o_lp);
  float* wavg  = (float*)(w + o_wavg);
  int*   h1    = (int*)(w + o_h1);
  int*   h2    = (int*)(w + o_h2);
  int*   cnts  = (int*)(w + o_cnt);
  int*   scal  = (int*)(w + o_scal);
  float* taup  = (float*)(scal + 8);

  hipMemsetAsync(w + zstart, 0, ztotal, stream);

  k1_wap  <<<nb, 256, 0, stream>>>(aw, wap, f0, scal + 0, B);
  k2_beta <<<(B + 3) / 4, 256, 0, stream>>>(an, nbr, att, proj, beta, B);
  k3a_hist<<<nb, 256, 0, stream>>>(beta, f0, h1, B);
  k3b_sel <<<1, 1024, 0, stream>>>(h1, scal);
  k3c_hist2<<<nb, 256, 0, stream>>>(beta, f0, scal, h2, B);
  k3d_tau <<<1, 1024, 0, stream>>>(h2, scal, taup);
  k4_q    <<<nb, 256, 0, stream>>>(wap, beta, f0, taup, qbuf, tgt, f1,
                                   scal + 1, cnts, bcnt, B);
  k5_scan <<<1, 256, 0, stream>>>(bcnt, boff, nb, cnts, scal + 1, wavg);
  k6_out  <<<nb, 256, 0, stream>>>(f1, tgt, labels, boff, astr, qbuf, wavg,
                                   out, lossp, n_host, B);
  k7_fin  <<<1, 256, 0, stream>>>(lossp, nb, scal + 1, out, n_host);
}

// Round 2
// 166.276 us; speedup vs baseline: 2.3264x; 2.3264x over previous
//
#include <hip/hip_runtime.h>
#include <math.h>

#define CC 10   // classes
#define KK 50   // neighbors

// ---------------- K1: softmax(anchors_weak) -> wap, mask0, b_count ----------
__global__ __launch_bounds__(256)
void k1_wap(const float* __restrict__ aw, float* __restrict__ wap,
            int* __restrict__ flag0, int* __restrict__ b_count, int B)
{
  int i = blockIdx.x * 256 + threadIdx.x;
  if (i >= B) return;
  float x[CC];
  const float2* p = reinterpret_cast<const float2*>(aw + (size_t)i * CC);
#pragma unroll
  for (int c = 0; c < CC / 2; ++c) { float2 t = p[c]; x[2 * c] = t.x; x[2 * c + 1] = t.y; }
  float m = x[0];
#pragma unroll
  for (int c = 1; c < CC; ++c) m = fmaxf(m, x[c]);
  float s = 0.f;
#pragma unroll
  for (int c = 0; c < CC; ++c) { x[c] = expf(x[c] - m); s += x[c]; }
  float mp = 0.f;
#pragma unroll
  for (int c = 0; c < CC; ++c) { x[c] = x[c] / s; mp = fmaxf(mp, x[c]); }
  float2* q = reinterpret_cast<float2*>(wap + (size_t)i * CC);
#pragma unroll
  for (int c = 0; c < CC / 2; ++c) { float2 t; t.x = x[2 * c]; t.y = x[2 * c + 1]; q[c] = t; }
  int f = (mp > 0.15f) ? 1 : 0;
  flag0[i] = f;
  if (f) atomicAdd(b_count, 1);   // uniform address -> wave-coalesced by compiler
}

// ---------------- K2: attention over neighbors -> beta[i] -------------------
// one wave (64 lanes) per row; lanes 0..49 handle the K neighbors
__global__ __launch_bounds__(256)
void k2_beta(const float* __restrict__ anchors, const float* __restrict__ neighbors,
             const float* __restrict__ att, const float* __restrict__ proj,
             float* __restrict__ beta, int B)
{
  __shared__ float coef[CC];
  if (threadIdx.x < CC) {
    float d = proj[threadIdx.x * CC + threadIdx.x];
    coef[threadIdx.x] = att[threadIdx.x] * d * d;
  }
  __syncthreads();
  int wave = threadIdx.x >> 6;
  int lane = threadIdx.x & 63;
  int row = blockIdx.x * 4 + wave;
  if (row >= B) return;

  float iv = (lane < CC) ? anchors[(size_t)row * CC + lane] : 0.f;
  float img[CC];
#pragma unroll
  for (int c = 0; c < CC; ++c) img[c] = __shfl(iv, c);

  bool act = (lane < KK);
  float nb[CC];
  if (act) {
    const float2* np_ = reinterpret_cast<const float2*>(neighbors + ((size_t)row * KK + lane) * CC);
#pragma unroll
    for (int c = 0; c < CC / 2; ++c) { float2 t = np_[c]; nb[2 * c] = t.x; nb[2 * c + 1] = t.y; }
  } else {
#pragma unroll
    for (int c = 0; c < CC; ++c) nb[c] = 0.f;
  }

  // att_score = leaky_relu( sum_c att[c]*d[c]^2 * img[c] * nb[c] )
  float s = 0.f;
#pragma unroll
  for (int c = 0; c < CC; ++c) s += coef[c] * img[c] * nb[c];
  s = (s > 0.f) ? s : 0.01f * s;

  // softmax over K (across lanes)
  float sm = act ? s : -INFINITY;
#pragma unroll
  for (int off = 32; off; off >>= 1) sm = fmaxf(sm, __shfl_xor(sm, off));
  float e = act ? expf(s - sm) : 0.f;
  float den = e;
#pragma unroll
  for (int off = 32; off; off >>= 1) den += __shfl_xor(den, off);
  float av = e / den;

  // nbp = softmax over C for this lane's neighbor
  float mx = nb[0];
#pragma unroll
  for (int c = 1; c < CC; ++c) mx = fmaxf(mx, nb[c]);
  float pn[CC]; float sn = 0.f;
#pragma unroll
  for (int c = 0; c < CC; ++c) { pn[c] = expf(nb[c] - mx); sn += pn[c]; }
  float scale = av / sn;
  float v[CC];
#pragma unroll
  for (int c = 0; c < CC; ++c) v[c] = act ? pn[c] * scale : 0.f;

  // q_hat[c] = sum_k att_val[k]*nbp[k,c]  (butterfly per component)
#pragma unroll
  for (int c = 0; c < CC; ++c) {
#pragma unroll
    for (int off = 32; off; off >>= 1) v[c] += __shfl_xor(v[c], off);
  }

  if (lane == 0) {
    float m2 = img[0];
#pragma unroll
    for (int c = 1; c < CC; ++c) m2 = fmaxf(m2, img[c]);
    float s2 = 0.f; float ap[CC];
#pragma unroll
    for (int c = 0; c < CC; ++c) { ap[c] = expf(img[c] - m2); s2 += ap[c]; }
    float bs = 0.f;
#pragma unroll
    for (int c = 0; c < CC; ++c) { float d = ap[c] / s2 - v[c]; bs += d * d; }
    beta[row] = bs;
  }
}

// ---------------- K3: exact radix select of k-th smallest beta --------------
__global__ __launch_bounds__(256)
void k3a_hist(const float* __restrict__ beta, const int* __restrict__ flag0,
              int* __restrict__ hist, int B)
{
  int i = blockIdx.x * 256 + threadIdx.x;
  if (i >= B) return;
  if (flag0[i]) {
    unsigned key = __float_as_uint(beta[i]);   // beta >= 0 -> bits are order-preserving
    atomicAdd(&hist[key >> 16], 1);
  }
}

// scal: [0]=b_count [1]=n_count [2]=sel_hi [3]=k2 [4]=k ; (float at [8]) = tau
__global__ __launch_bounds__(1024)
void k3b_sel(const int* __restrict__ hist, int* __restrict__ scal)
{
  __shared__ int tmp[1024];
  int t = threadIdx.x;
  int base = t * 64;
  int sum = 0;
  for (int j = 0; j < 64; ++j) sum += hist[base + j];
  tmp[t] = sum;
  __syncthreads();
  for (int off = 1; off < 1024; off <<= 1) {
    int v = (t >= off) ? tmp[t - off] : 0;
    __syncthreads();
    tmp[t] += v;
    __syncthreads();
  }
  int cumb = tmp[t] - sum;
  int b = scal[0];
  int k = (int)(0.5 * (double)b);   // int(ETA*b)
  if (k < 1) k = 1;
  if (t == 0) scal[4] = k;
  if (b > 0 && k > cumb && k <= cumb + sum) {
    int c = cumb;
    for (int j = 0; j < 64; ++j) {
      int h = hist[base + j];
      if (k <= c + h) { scal[2] = base + j; scal[3] = k - c; break; }
      c += h;
    }
  }
  if (b == 0 && t == 0) { scal[2] = 0; scal[3] = 1; }
}

__global__ __launch_bounds__(256)
void k3c_hist2(const float* __restrict__ beta, const int* __restrict__ flag0,
               const int* __restrict__ scal, int* __restrict__ hist2, int B)
{
  int i = blockIdx.x * 256 + threadIdx.x;
  if (i >= B) return;
  if (flag0[i]) {
    unsigned key = __float_as_uint(beta[i]);
    if ((int)(key >> 16) == scal[2]) atomicAdd(&hist2[key & 0xFFFF], 1);
  }
}

__global__ __launch_bounds__(1024)
void k3d_tau(const int* __restrict__ hist2, int* __restrict__ scal,
             float* __restrict__ tau)
{
  __shared__ int tmp[1024];
  int t = threadIdx.x;
  int base = t * 64;
  int sum = 0;
  for (int j = 0; j < 64; ++j) sum += hist2[base + j];
  tmp[t] = sum;
  __syncthreads();
  for (int off = 1; off < 1024; off <<= 1) {
    int v = (t >= off) ? tmp[t - off] : 0;
    __syncthreads();
    tmp[t] += v;
    __syncthreads();
  }
  int cumb = tmp[t] - sum;
  int k2 = scal[3];
  if (k2 > cumb && k2 <= cumb + sum) {
    int c = cumb;
    for (int j = 0; j < 64; ++j) {
      int h = hist2[base + j];
      if (k2 <= c + h) {
        unsigned key = (((unsigned)scal[2]) << 16) | (unsigned)(base + j);
        float bk = __uint_as_float(key);
        *tau = bk / expf(-1.0f);
        break;
      }
      c += h;
    }
  }
}

// ---------------- K4: q, target, mask1, per-block counts --------------------
__global__ __launch_bounds__(256)
void k4_q(const float* __restrict__ wap, const float* __restrict__ beta,
          const int* __restrict__ flag0, const float* __restrict__ tau_p,
          float* __restrict__ qbuf, int* __restrict__ target, int* __restrict__ flag1,
          int* __restrict__ counts, int* __restrict__ blockcnt, int B)
{
  __shared__ int lcnt[CC];
  if (threadIdx.x < CC) lcnt[threadIdx.x] = 0;
  __syncthreads();

  int i = blockIdx.x * 256 + threadIdx.x;
  int f = 0;
  if (i < B) {
    float tau = *tau_p;
    float w[CC];
    const float2* p = reinterpret_cast<const float2*>(wap + (size_t)i * CC);
#pragma unroll
    for (int c = 0; c < CC / 2; ++c) { float2 t = p[c]; w[2 * c] = t.x; w[2 * c + 1] = t.y; }
    float alpha = -logf(beta[i] / tau);
    float q[CC];
    if (alpha > 1.0f) {
      float s = 0.f;
#pragma unroll
      for (int c = 0; c < CC; ++c) { q[c] = powf(w[c], alpha); s += q[c]; }
#pragma unroll
      for (int c = 0; c < CC; ++c) q[c] = q[c] / s;
    } else {
#pragma unroll
      for (int c = 0; c < CC; ++c) q[c] = w[c];
    }
    float mp = q[0]; int tg = 0;
#pragma unroll
    for (int c = 1; c < CC; ++c) if (q[c] > mp) { mp = q[c]; tg = c; }
    f = (flag0[i] && (mp > 0.1f)) ? 1 : 0;
    float2* qo = reinterpret_cast<float2*>(qbuf + (size_t)i * CC);
#pragma unroll
    for (int c = 0; c < CC / 2; ++c) { float2 t; t.x = q[2 * c]; t.y = q[2 * c + 1]; qo[c] = t; }
    target[i] = tg;
    flag1[i] = f;
    if (f) atomicAdd(&lcnt[tg], 1);   // LDS atomic: cheap, contained in block
  }
  __shared__ int red[256];
  red[threadIdx.x] = f;
  __syncthreads();
  for (int off = 128; off; off >>= 1) {
    if (threadIdx.x < off) red[threadIdx.x] += red[threadIdx.x + off];
    __syncthreads();
  }
  if (threadIdx.x == 0) blockcnt[blockIdx.x] = red[0];
  if (threadIdx.x < CC) {
    int v = lcnt[threadIdx.x];
    if (v) atomicAdd(&counts[threadIdx.x], v);   // <=10 global atomics per block
  }
}

// ---------------- K5: scan block counts; n; class weights -------------------
__global__ __launch_bounds__(256)
void k5_scan(const int* __restrict__ blockcnt, int* __restrict__ blockoff, int nb,
             const int* __restrict__ counts, int* __restrict__ n_out,
             float* __restrict__ wavg)
{
  __shared__ int tmp[256];
  int t = threadIdx.x;
  int v = (t < nb) ? blockcnt[t] : 0;
  tmp[t] = v;
  __syncthreads();
  for (int off = 1; off < 256; off <<= 1) {
    int u = (t >= off) ? tmp[t - off] : 0;
    __syncthreads();
    tmp[t] += u;
    __syncthreads();
  }
  if (t < nb) blockoff[t] = tmp[t] - v;
  if (t == 0) {
    int n = tmp[255];           // total over all blocks
    *n_out = n;
    float wt[CC]; float sumw = 0.f;
    for (int c = 0; c < CC; ++c) {
      int cnt = counts[c];
      float w_;
      if (cnt > 0) {
        float freq = (float)cnt / (float)n;
        w_ = 1.0f / logf(1.02f + freq);
      } else {
        w_ = 1.0f;
      }
      wt[c] = w_; sumw += w_;
    }
    float meanw = sumw / (float)CC;
    for (int c = 0; c < CC; ++c) wavg[c] = wt[c] / sumw * meanw;
  }
}

// ---------------- K6: compacted outputs + loss partials ---------------------
__global__ __launch_bounds__(256)
void k6_out(const int* __restrict__ flag1, const int* __restrict__ target,
            const int* __restrict__ labels, const int* __restrict__ blockoff,
            const float* __restrict__ a_strong, const float* __restrict__ qbuf,
            const float* __restrict__ wavg, float* __restrict__ out,
            float* __restrict__ lossp, int n_host, int B)
{
  int i = blockIdx.x * 256 + threadIdx.x;
  int t = threadIdx.x;
  int f = (i < B) ? flag1[i] : 0;
  __shared__ int tmp[256];
  tmp[t] = f;
  __syncthreads();
  for (int off = 1; off < 256; off <<= 1) {
    int u = (t >= off) ? tmp[t - off] : 0;
    __syncthreads();
    tmp[t] += u;
    __syncthreads();
  }
  int pos = blockoff[blockIdx.x] + tmp[t] - f;
  float part = 0.f;
  if (f) {
    out[1 + pos] = (float)target[i];
    out[1 + n_host + pos] = (float)labels[i];
    float x[CC];
    const float2* p = reinterpret_cast<const float2*>(a_strong + (size_t)i * CC);
#pragma unroll
    for (int c = 0; c < CC / 2; ++c) { float2 u2 = p[c]; x[2 * c] = u2.x; x[2 * c + 1] = u2.y; }
    float m = x[0];
#pragma unroll
    for (int c = 1; c < CC; ++c) m = fmaxf(m, x[c]);
    float s = 0.f;
#pragma unroll
    for (int c = 0; c < CC; ++c) s += expf(x[c] - m);
    float lse = m + logf(s);
    const float2* qp = reinterpret_cast<const float2*>(qbuf + (size_t)i * CC);
    float q[CC];
#pragma unroll
    for (int c = 0; c < CC / 2; ++c) { float2 u2 = qp[c]; q[2 * c] = u2.x; q[2 * c + 1] = u2.y; }
#pragma unroll
    for (int c = 0; c < CC; ++c) part += wavg[c] * q[c] * (x[c] - lse);
  }
  __shared__ float red[256];
  red[t] = part;
  __syncthreads();
  for (int off = 128; off; off >>= 1) {
    if (t < off) red[t] += red[t + off];
    __syncthreads();
  }
  if (t == 0) lossp[blockIdx.x] = red[0];
}

// ---------------- K7: finalize ----------------------------------------------
__global__ __launch_bounds__(256)
void k7_fin(const float* __restrict__ lossp, int nb, const int* __restrict__ n_count,
            float* __restrict__ out, int n_host)
{
  __shared__ float red[256];
  int t = threadIdx.x;
  float s = 0.f;
  for (int j = t; j < nb; j += 256) s += lossp[j];
  red[t] = s;
  __syncthreads();
  for (int off = 128; off; off >>= 1) {
    if (t < off) red[t] += red[t + off];
    __syncthreads();
  }
  if (t == 0) {
    int n = *n_count;
    out[0] = -red[0] / (float)n;
    out[1 + 2 * n_host] = (float)n;
  }
}

extern "C" void kernel_launch(void* const* d_in, const int* in_sizes, int n_in,
                              void* d_out, int out_size, void* d_ws, size_t ws_size,
                              hipStream_t stream)
{
  const float* aw     = (const float*)d_in[0];
  const float* astr   = (const float*)d_in[1];
  const float* an     = (const float*)d_in[2];
  const float* nbr    = (const float*)d_in[3];
  const int*   labels = (const int*)d_in[4];
  const float* att    = (const float*)d_in[6];
  const float* proj   = (const float*)d_in[7];
  float* out = (float*)d_out;

  int B = in_sizes[4];
  int C = in_sizes[6];
  int K = (B > 0 && C > 0) ? in_sizes[3] / (B * C) : 0;
  if (C != CC || K != KK) return;
  int n_host = (out_size - 2) / 2;
  int nb = (B + 255) / 256;
  if (nb > 256) return;

  char* w = (char*)d_ws;
  size_t o = 0;
  auto alloc = [&](size_t bytes) { size_t r = o; o += (bytes + 255) & ~(size_t)255; return r; };
  size_t o_wap  = alloc((size_t)B * CC * 4);
  size_t o_q    = alloc((size_t)B * CC * 4);
  size_t o_beta = alloc((size_t)B * 4);
  size_t o_tgt  = alloc((size_t)B * 4);
  size_t o_f0   = alloc((size_t)B * 4);
  size_t o_f1   = alloc((size_t)B * 4);
  size_t o_bc   = alloc((size_t)nb * 4);
  size_t o_bo   = alloc((size_t)nb * 4);
  size_t o_lp   = alloc((size_t)nb * 4);
  size_t o_wavg = alloc(64);
  size_t zstart = o;
  size_t o_h1   = alloc(65536 * 4);
  size_t o_h2   = alloc(65536 * 4);
  size_t o_cnt  = alloc(64);
  size_t o_scal = alloc(64);
  size_t ztotal = o - zstart;
  if (o > ws_size) return;

  float* wap   = (float*)(w + o_wap);
  float* qbuf  = (float*)(w + o_q);
  float* beta  = (float*)(w + o_beta);
  int*   tgt   = (int*)(w + o_tgt);
  int*   f0    = (int*)(w + o_f0);
  int*   f1    = (int*)(w + o_f1);
  int*   bcnt  = (int*)(w + o_bc);
  int*   boff  = (int*)(w + o_bo);
  float* lossp = (float*)(w + o_lp);
  float* wavg  = (float*)(w + o_wavg);
  int*   h1    = (int*)(w + o_h1);
  int*   h2    = (int*)(w + o_h2);
  int*   cnts  = (int*)(w + o_cnt);
  int*   scal  = (int*)(w + o_scal);
  float* taup  = (float*)(scal + 8);

  hipMemsetAsync(w + zstart, 0, ztotal, stream);

  k1_wap  <<<nb, 256, 0, stream>>>(aw, wap, f0, scal + 0, B);
  k2_beta <<<(B + 3) / 4, 256, 0, stream>>>(an, nbr, att, proj, beta, B);
  k3a_hist<<<nb, 256, 0, stream>>>(beta, f0, h1, B);
  k3b_sel <<<1, 1024, 0, stream>>>(h1, scal);
  k3c_hist2<<<nb, 256, 0, stream>>>(beta, f0, scal, h2, B);
  k3d_tau <<<1, 1024, 0, stream>>>(h2, scal, taup);
  k4_q    <<<nb, 256, 0, stream>>>(wap, beta, f0, taup, qbuf, tgt, f1,
                                   cnts, bcnt, B);
  k5_scan <<<1, 256, 0, stream>>>(bcnt, boff, nb, cnts, scal + 1, wavg);
  k6_out  <<<nb, 256, 0, stream>>>(f1, tgt, labels, boff, astr, qbuf, wavg,
                                   out, lossp, n_host, B);
  k7_fin  <<<1, 256, 0, stream>>>(lossp, nb, scal + 1, out, n_host);
}

// Round 3
// 136.840 us; speedup vs baseline: 2.8268x; 1.2151x over previous
//
#include <hip/hip_runtime.h>
#include <math.h>

#define CC 10   // classes
#define KK 50   // neighbors
#define TPR 4   // threads per row in kA

// ---- kA: fused wap/flag0 + online-softmax attention beta + hist ------------
// 4 threads per row; each runs online softmax over k in {j, j+4, ...};
// merge (m, den, qh[]) across the 4 lanes with a 2-step butterfly.
__global__ __launch_bounds__(256)
void kA(const float* __restrict__ aw, const float* __restrict__ an,
        const float* __restrict__ nbr, const float* __restrict__ att,
        const float* __restrict__ proj,
        float* __restrict__ wap, float* __restrict__ beta,
        int* __restrict__ flag0, int* __restrict__ scal,
        int* __restrict__ hist, int B)
{
  __shared__ float coef[CC];
  if (threadIdx.x < CC) {
    float d = proj[threadIdx.x * CC + threadIdx.x];
    coef[threadIdx.x] = att[threadIdx.x] * d * d;
  }
  __syncthreads();

  int gt  = blockIdx.x * 256 + threadIdx.x;
  int row = gt >> 2;
  int j   = gt & (TPR - 1);
  if (row >= B) return;

  // anchors row (all 4 lanes load; L1 absorbs the redundancy)
  float img[CC];
  {
    const float2* p = reinterpret_cast<const float2*>(an + (size_t)row * CC);
#pragma unroll
    for (int c = 0; c < CC / 2; ++c) { float2 t = p[c]; img[2*c] = t.x; img[2*c+1] = t.y; }
  }
  float ci[CC];
#pragma unroll
  for (int c = 0; c < CC; ++c) ci[c] = coef[c] * img[c];

  // online softmax-weighted sum over this lane's neighbors
  float m = -INFINITY, den = 0.f;
  float qh[CC];
#pragma unroll
  for (int c = 0; c < CC; ++c) qh[c] = 0.f;

  for (int k = j; k < KK; k += TPR) {
    float nb[CC];
    const float2* p = reinterpret_cast<const float2*>(nbr + ((size_t)row * KK + k) * CC);
#pragma unroll
    for (int c = 0; c < CC / 2; ++c) { float2 t = p[c]; nb[2*c] = t.x; nb[2*c+1] = t.y; }

    float s = 0.f;
#pragma unroll
    for (int c = 0; c < CC; ++c) s = fmaf(ci[c], nb[c], s);
    s = (s > 0.f) ? s : 0.01f * s;                 // leaky_relu

    float mx = nb[0];
#pragma unroll
    for (int c = 1; c < CC; ++c) mx = fmaxf(mx, nb[c]);
    float en[CC]; float sn = 0.f;
#pragma unroll
    for (int c = 0; c < CC; ++c) { en[c] = expf(nb[c] - mx); sn += en[c]; }

    if (s > m) {
      float corr = expf(m - s);                    // expf(-inf)=0 on first iter
      den *= corr;
#pragma unroll
      for (int c = 0; c < CC; ++c) qh[c] *= corr;
      m = s;
    }
    float e   = expf(s - m);
    den += e;
    float esc = e / sn;
#pragma unroll
    for (int c = 0; c < CC; ++c) qh[c] = fmaf(esc, en[c], qh[c]);
  }

  // merge the 4 per-lane online states (lanes differ in bits 0..1)
#pragma unroll
  for (int off = 1; off <= 2; off <<= 1) {
    float mo   = __shfl_xor(m, off);
    float deno = __shfl_xor(den, off);
    float qho[CC];
#pragma unroll
    for (int c = 0; c < CC; ++c) qho[c] = __shfl_xor(qh[c], off);
    float mn = fmaxf(m, mo);
    float c1 = expf(m - mn), c2 = expf(mo - mn);
    den = den * c1 + deno * c2;
#pragma unroll
    for (int c = 0; c < CC; ++c) qh[c] = qh[c] * c1 + qho[c] * c2;
    m = mn;
  }

  if (j == 0) {
    // beta = || softmax(anchors) - q_hat ||^2
    float m2 = img[0];
#pragma unroll
    for (int c = 1; c < CC; ++c) m2 = fmaxf(m2, img[c]);
    float s2 = 0.f; float ap[CC];
#pragma unroll
    for (int c = 0; c < CC; ++c) { ap[c] = expf(img[c] - m2); s2 += ap[c]; }
    float inv2 = 1.f / s2, invd = 1.f / den;
    float bs = 0.f;
#pragma unroll
    for (int c = 0; c < CC; ++c) { float d = ap[c] * inv2 - qh[c] * invd; bs += d * d; }
    beta[row] = bs;

    // wap = softmax(anchors_weak), flag0, b_count, hist of beta hi-16
    float x[CC];
    const float2* p = reinterpret_cast<const float2*>(aw + (size_t)row * CC);
#pragma unroll
    for (int c = 0; c < CC / 2; ++c) { float2 t = p[c]; x[2*c] = t.x; x[2*c+1] = t.y; }
    float mw = x[0];
#pragma unroll
    for (int c = 1; c < CC; ++c) mw = fmaxf(mw, x[c]);
    float sw = 0.f;
#pragma unroll
    for (int c = 0; c < CC; ++c) { x[c] = expf(x[c] - mw); sw += x[c]; }
    float isw = 1.f / sw; float mp = 0.f;
#pragma unroll
    for (int c = 0; c < CC; ++c) { x[c] *= isw; mp = fmaxf(mp, x[c]); }
    float2* q = reinterpret_cast<float2*>(wap + (size_t)row * CC);
#pragma unroll
    for (int c = 0; c < CC / 2; ++c) { float2 t; t.x = x[2*c]; t.y = x[2*c+1]; q[c] = t; }
    int f = (mp > 0.15f) ? 1 : 0;
    flag0[row] = f;
    if (f) {
      atomicAdd(&scal[0], 1);
      unsigned key = __float_as_uint(bs);   // beta >= 0 -> order-preserving bits
      atomicAdd(&hist[key >> 16], 1);
    }
  }
}

// ---------------- K3: exact radix select of k-th smallest beta --------------
// scal: [0]=b_count [1]=n_count [2]=sel_hi [3]=k2 [4]=k ; (float at [8]) = tau
__global__ __launch_bounds__(1024)
void k3b_sel(const int* __restrict__ hist, int* __restrict__ scal,
             int* __restrict__ hist2_zero)
{
  __shared__ int tmp[1024];
  int t = threadIdx.x;
  // zero hist2 for the next pass (saves half the memset)
  for (int jj = 0; jj < 64; ++jj) hist2_zero[t * 64 + jj] = 0;
  int base = t * 64;
  int sum = 0;
  for (int jj = 0; jj < 64; ++jj) sum += hist[base + jj];
  tmp[t] = sum;
  __syncthreads();
  for (int off = 1; off < 1024; off <<= 1) {
    int v = (t >= off) ? tmp[t - off] : 0;
    __syncthreads();
    tmp[t] += v;
    __syncthreads();
  }
  int cumb = tmp[t] - sum;
  int b = scal[0];
  int k = (int)(0.5 * (double)b);   // int(ETA*b)
  if (k < 1) k = 1;
  if (t == 0) scal[4] = k;
  if (b > 0 && k > cumb && k <= cumb + sum) {
    int c = cumb;
    for (int jj = 0; jj < 64; ++jj) {
      int h = hist[base + jj];
      if (k <= c + h) { scal[2] = base + jj; scal[3] = k - c; break; }
      c += h;
    }
  }
  if (b == 0 && t == 0) { scal[2] = 0; scal[3] = 1; }
}

__global__ __launch_bounds__(256)
void k3c_hist2(const float* __restrict__ beta, const int* __restrict__ flag0,
               const int* __restrict__ scal, int* __restrict__ hist2, int B)
{
  int i = blockIdx.x * 256 + threadIdx.x;
  if (i >= B) return;
  if (flag0[i]) {
    unsigned key = __float_as_uint(beta[i]);
    if ((int)(key >> 16) == scal[2]) atomicAdd(&hist2[key & 0xFFFF], 1);
  }
}

__global__ __launch_bounds__(1024)
void k3d_tau(const int* __restrict__ hist2, int* __restrict__ scal,
             float* __restrict__ tau)
{
  __shared__ int tmp[1024];
  int t = threadIdx.x;
  int base = t * 64;
  int sum = 0;
  for (int jj = 0; jj < 64; ++jj) sum += hist2[base + jj];
  tmp[t] = sum;
  __syncthreads();
  for (int off = 1; off < 1024; off <<= 1) {
    int v = (t >= off) ? tmp[t - off] : 0;
    __syncthreads();
    tmp[t] += v;
    __syncthreads();
  }
  int cumb = tmp[t] - sum;
  int k2 = scal[3];
  if (k2 > cumb && k2 <= cumb + sum) {
    int c = cumb;
    for (int jj = 0; jj < 64; ++jj) {
      int h = hist2[base + jj];
      if (k2 <= c + h) {
        unsigned key = (((unsigned)scal[2]) << 16) | (unsigned)(base + jj);
        float bk = __uint_as_float(key);
        *tau = bk / expf(-1.0f);
        break;
      }
      c += h;
    }
  }
}

// ---------------- K4: q, target, mask1, per-block counts --------------------
__global__ __launch_bounds__(256)
void k4_q(const float* __restrict__ wap, const float* __restrict__ beta,
          const int* __restrict__ flag0, const float* __restrict__ tau_p,
          float* __restrict__ qbuf, int* __restrict__ target, int* __restrict__ flag1,
          int* __restrict__ counts, int* __restrict__ blockcnt, int B)
{
  __shared__ int lcnt[CC];
  if (threadIdx.x < CC) lcnt[threadIdx.x] = 0;
  __syncthreads();

  int i = blockIdx.x * 256 + threadIdx.x;
  int f = 0;
  if (i < B) {
    float tau = *tau_p;
    float w[CC];
    const float2* p = reinterpret_cast<const float2*>(wap + (size_t)i * CC);
#pragma unroll
    for (int c = 0; c < CC / 2; ++c) { float2 t = p[c]; w[2*c] = t.x; w[2*c+1] = t.y; }
    float alpha = -logf(beta[i] / tau);
    float q[CC];
    if (alpha > 1.0f) {
      float s = 0.f;
#pragma unroll
      for (int c = 0; c < CC; ++c) { q[c] = powf(w[c], alpha); s += q[c]; }
#pragma unroll
      for (int c = 0; c < CC; ++c) q[c] = q[c] / s;
    } else {
#pragma unroll
      for (int c = 0; c < CC; ++c) q[c] = w[c];
    }
    float mp = q[0]; int tg = 0;
#pragma unroll
    for (int c = 1; c < CC; ++c) if (q[c] > mp) { mp = q[c]; tg = c; }
    f = (flag0[i] && (mp > 0.1f)) ? 1 : 0;
    float2* qo = reinterpret_cast<float2*>(qbuf + (size_t)i * CC);
#pragma unroll
    for (int c = 0; c < CC / 2; ++c) { float2 t; t.x = q[2*c]; t.y = q[2*c+1]; qo[c] = t; }
    target[i] = tg;
    flag1[i] = f;
    if (f) atomicAdd(&lcnt[tg], 1);   // LDS atomic, contained in block
  }
  __shared__ int red[256];
  red[threadIdx.x] = f;
  __syncthreads();
  for (int off = 128; off; off >>= 1) {
    if (threadIdx.x < off) red[threadIdx.x] += red[threadIdx.x + off];
    __syncthreads();
  }
  if (threadIdx.x == 0) blockcnt[blockIdx.x] = red[0];
  if (threadIdx.x < CC) {
    int v = lcnt[threadIdx.x];
    if (v) atomicAdd(&counts[threadIdx.x], v);   // <=10 global atomics per block
  }
}

// ---------------- K5: scan block counts; n; class weights -------------------
__global__ __launch_bounds__(256)
void k5_scan(const int* __restrict__ blockcnt, int* __restrict__ blockoff, int nb,
             const int* __restrict__ counts, int* __restrict__ n_out,
             float* __restrict__ wavg)
{
  __shared__ int tmp[256];
  int t = threadIdx.x;
  int v = (t < nb) ? blockcnt[t] : 0;
  tmp[t] = v;
  __syncthreads();
  for (int off = 1; off < 256; off <<= 1) {
    int u = (t >= off) ? tmp[t - off] : 0;
    __syncthreads();
    tmp[t] += u;
    __syncthreads();
  }
  if (t < nb) blockoff[t] = tmp[t] - v;
  if (t == 0) {
    int n = tmp[255];
    *n_out = n;
    float wt[CC]; float sumw = 0.f;
    for (int c = 0; c < CC; ++c) {
      int cnt = counts[c];
      float w_;
      if (cnt > 0) {
        float freq = (float)cnt / (float)n;
        w_ = 1.0f / logf(1.02f + freq);
      } else {
        w_ = 1.0f;
      }
      wt[c] = w_; sumw += w_;
    }
    float meanw = sumw / (float)CC;
    for (int c = 0; c < CC; ++c) wavg[c] = wt[c] / sumw * meanw;
  }
}

// ---------------- K6: compacted outputs + loss partials ---------------------
__global__ __launch_bounds__(256)
void k6_out(const int* __restrict__ flag1, const int* __restrict__ target,
            const int* __restrict__ labels, const int* __restrict__ blockoff,
            const float* __restrict__ a_strong, const float* __restrict__ qbuf,
            const float* __restrict__ wavg, float* __restrict__ out,
            float* __restrict__ lossp, int n_host, int B)
{
  int i = blockIdx.x * 256 + threadIdx.x;
  int t = threadIdx.x;
  int f = (i < B) ? flag1[i] : 0;
  __shared__ int tmp[256];
  tmp[t] = f;
  __syncthreads();
  for (int off = 1; off < 256; off <<= 1) {
    int u = (t >= off) ? tmp[t - off] : 0;
    __syncthreads();
    tmp[t] += u;
    __syncthreads();
  }
  int pos = blockoff[blockIdx.x] + tmp[t] - f;
  float part = 0.f;
  if (f) {
    out[1 + pos] = (float)target[i];
    out[1 + n_host + pos] = (float)labels[i];
    float x[CC];
    const float2* p = reinterpret_cast<const float2*>(a_strong + (size_t)i * CC);
#pragma unroll
    for (int c = 0; c < CC / 2; ++c) { float2 u2 = p[c]; x[2*c] = u2.x; x[2*c+1] = u2.y; }
    float m = x[0];
#pragma unroll
    for (int c = 1; c < CC; ++c) m = fmaxf(m, x[c]);
    float s = 0.f;
#pragma unroll
    for (int c = 0; c < CC; ++c) s += expf(x[c] - m);
    float lse = m + logf(s);
    const float2* qp = reinterpret_cast<const float2*>(qbuf + (size_t)i * CC);
    float q[CC];
#pragma unroll
    for (int c = 0; c < CC / 2; ++c) { float2 u2 = qp[c]; q[2*c] = u2.x; q[2*c+1] = u2.y; }
#pragma unroll
    for (int c = 0; c < CC; ++c) part += wavg[c] * q[c] * (x[c] - lse);
  }
  __shared__ float red[256];
  red[t] = part;
  __syncthreads();
  for (int off = 128; off; off >>= 1) {
    if (t < off) red[t] += red[t + off];
    __syncthreads();
  }
  if (t == 0) lossp[blockIdx.x] = red[0];
}

// ---------------- K7: finalize ----------------------------------------------
__global__ __launch_bounds__(256)
void k7_fin(const float* __restrict__ lossp, int nb, const int* __restrict__ n_count,
            float* __restrict__ out, int n_host)
{
  __shared__ float red[256];
  int t = threadIdx.x;
  float s = 0.f;
  for (int jj = t; jj < nb; jj += 256) s += lossp[jj];
  red[t] = s;
  __syncthreads();
  for (int off = 128; off; off >>= 1) {
    if (t < off) red[t] += red[t + off];
    __syncthreads();
  }
  if (t == 0) {
    int n = *n_count;
    out[0] = -red[0] / (float)n;
    out[1 + 2 * n_host] = (float)n;
  }
}

extern "C" void kernel_launch(void* const* d_in, const int* in_sizes, int n_in,
                              void* d_out, int out_size, void* d_ws, size_t ws_size,
                              hipStream_t stream)
{
  const float* aw     = (const float*)d_in[0];
  const float* astr   = (const float*)d_in[1];
  const float* an     = (const float*)d_in[2];
  const float* nbr    = (const float*)d_in[3];
  const int*   labels = (const int*)d_in[4];
  const float* att    = (const float*)d_in[6];
  const float* proj   = (const float*)d_in[7];
  float* out = (float*)d_out;

  int B = in_sizes[4];
  int C = in_sizes[6];
  int K = (B > 0 && C > 0) ? in_sizes[3] / (B * C) : 0;
  if (C != CC || K != KK) return;
  int n_host = (out_size - 2) / 2;
  int nb = (B + 255) / 256;
  if (nb > 256) return;

  char* w = (char*)d_ws;
  size_t o = 0;
  auto alloc = [&](size_t bytes) { size_t r = o; o += (bytes + 255) & ~(size_t)255; return r; };
  size_t o_wap  = alloc((size_t)B * CC * 4);
  size_t o_q    = alloc((size_t)B * CC * 4);
  size_t o_beta = alloc((size_t)B * 4);
  size_t o_tgt  = alloc((size_t)B * 4);
  size_t o_f0   = alloc((size_t)B * 4);
  size_t o_f1   = alloc((size_t)B * 4);
  size_t o_bc   = alloc((size_t)nb * 4);
  size_t o_bo   = alloc((size_t)nb * 4);
  size_t o_lp   = alloc((size_t)nb * 4);
  size_t o_wavg = alloc(64);
  size_t zstart = o;                       // zeroed-by-memset region: h1,cnt,scal
  size_t o_h1   = alloc(65536 * 4);
  size_t o_cnt  = alloc(64);
  size_t o_scal = alloc(64);
  size_t ztotal = o - zstart;
  size_t o_h2   = alloc(65536 * 4);        // zeroed inside k3b_sel
  if (o > ws_size) return;

  float* wap   = (float*)(w + o_wap);
  float* qbuf  = (float*)(w + o_q);
  float* beta  = (float*)(w + o_beta);
  int*   tgt   = (int*)(w + o_tgt);
  int*   f0    = (int*)(w + o_f0);
  int*   f1    = (int*)(w + o_f1);
  int*   bcnt  = (int*)(w + o_bc);
  int*   boff  = (int*)(w + o_bo);
  float* lossp = (float*)(w + o_lp);
  float* wavg  = (float*)(w + o_wavg);
  int*   h1    = (int*)(w + o_h1);
  int*   h2    = (int*)(w + o_h2);
  int*   cnts  = (int*)(w + o_cnt);
  int*   scal  = (int*)(w + o_scal);
  float* taup  = (float*)(scal + 8);

  hipMemsetAsync(w + zstart, 0, ztotal, stream);

  int nbA = (B * TPR + 255) / 256;
  kA      <<<nbA, 256, 0, stream>>>(aw, an, nbr, att, proj, wap, beta, f0, scal, h1, B);
  k3b_sel <<<1, 1024, 0, stream>>>(h1, scal, h2);
  k3c_hist2<<<nb, 256, 0, stream>>>(beta, f0, scal, h2, B);
  k3d_tau <<<1, 1024, 0, stream>>>(h2, scal, taup);
  k4_q    <<<nb, 256, 0, stream>>>(wap, beta, f0, taup, qbuf, tgt, f1,
                                   cnts, bcnt, B);
  k5_scan <<<1, 256, 0, stream>>>(bcnt, boff, nb, cnts, scal + 1, wavg);
  k6_out  <<<nb, 256, 0, stream>>>(f1, tgt, labels, boff, astr, qbuf, wavg,
                                   out, lossp, n_host, B);
  k7_fin  <<<1, 256, 0, stream>>>(lossp, nb, scal + 1, out, n_host);
}